// Round 1
// baseline (371.765 us; speedup 1.0000x reference)
//
#include <hip/hip_runtime.h>
#include <stdint.h>

#define NT 256
#define BIG_BLOCKS 2048

// meta slot indices (all zero-initialized each launch)
enum {
  M_B1 = 0,   // level-1 bin (top 12 bits)
  M_C1,       // count of elements strictly below bin b1
  M_B2,       // level-2 bin (mid 12 bits)
  M_C2,       // count strictly below (b1,b2) prefix
  M_B3,       // level-3 bin (low 8 bits)
  M_V,        // exact cutoff bit pattern
  M_NLESS,    // count of u < v
  M_NTIE,     // count of u == v
  M_NTZ,      // number of ties that get 0 (= j - nLess)
  M_ITHR,     // tie index threshold: tie gets 1 iff idx >= I_thr
  M_CAND2,    // level-2 candidate count
  M_OVF,      // level-1 candidate buffer overflow flag
  M_NMETA
};

__global__ void k_zero(uint32_t* p, int n) {
  int i = blockIdx.x * NT + threadIdx.x;
  if (i < n) p[i] = 0;
}

// ---------------- Pass 1: histogram of top-12 bits of u = |bits| ----------------
__global__ void k_hist1(const uint32_t* __restrict__ param, long long n4,
                        uint32_t* __restrict__ hist1) {
  __shared__ uint32_t h[2048];  // u <= 0x7fffffff -> u>>20 <= 2047
  for (int i = threadIdx.x; i < 2048; i += NT) h[i] = 0;
  __syncthreads();
  const uint4* p4 = (const uint4*)param;
  long long stride = (long long)gridDim.x * NT;
  for (long long i = (long long)blockIdx.x * NT + threadIdx.x; i < n4; i += stride) {
    uint4 w = p4[i];
    atomicAdd(&h[(w.x & 0x7fffffffu) >> 20], 1u);
    atomicAdd(&h[(w.y & 0x7fffffffu) >> 20], 1u);
    atomicAdd(&h[(w.z & 0x7fffffffu) >> 20], 1u);
    atomicAdd(&h[(w.w & 0x7fffffffu) >> 20], 1u);
  }
  __syncthreads();
  for (int i = threadIdx.x; i < 2048; i += NT)
    if (h[i]) atomicAdd(&hist1[i], h[i]);
}

// ------------- generic single-block bin selector: find bin where cumulative
// count crosses rank j; writes chosen bin and cumulative-before-bin -------------
__global__ void k_select(const uint32_t* __restrict__ hist, int nbins,
                         const uint32_t* basePtr, uint32_t jrank,
                         uint32_t* outBin, uint32_t* outCum) {
  __shared__ uint32_t part[NT];
  int per = nbins / NT;
  uint32_t base = basePtr ? *basePtr : 0u;
  uint32_t s = 0;
  int lo = threadIdx.x * per, hi = lo + per;
  for (int b = lo; b < hi; ++b) s += hist[b];
  part[threadIdx.x] = s;
  __syncthreads();
  for (int off = 1; off < NT; off <<= 1) {
    uint32_t y = (threadIdx.x >= (unsigned)off) ? part[threadIdx.x - off] : 0u;
    __syncthreads();
    part[threadIdx.x] += y;
    __syncthreads();
  }
  uint32_t cum = base + part[threadIdx.x] - s;  // exclusive prefix of my chunk
  for (int b = lo; b < hi; ++b) {
    uint32_t hv = hist[b];
    if (cum <= jrank && jrank < cum + hv) { *outBin = (uint32_t)b; *outCum = cum; }
    cum += hv;
  }
}

// ------- Pass 2: compact level-1 candidates into per-block regions + hist2 -------
__global__ void k_pass2(const uint32_t* __restrict__ param, long long n,
                        uint32_t* __restrict__ meta, uint32_t* __restrict__ hist2,
                        uint2* __restrict__ candBuf, uint32_t perBlockCap,
                        uint32_t* __restrict__ blockCounts) {
  __shared__ uint32_t h[4096];
  __shared__ uint32_t lcount;
  __shared__ uint32_t sb1;
  if (threadIdx.x == 0) { lcount = 0; sb1 = meta[M_B1]; }
  for (int i = threadIdx.x; i < 4096; i += NT) h[i] = 0;
  __syncthreads();
  uint32_t b1 = sb1;
  const uint4* p4 = (const uint4*)param;
  long long n4 = n >> 2;
  long long per = (n4 + gridDim.x - 1) / gridDim.x;
  long long lo = (long long)blockIdx.x * per;
  long long hiB = lo + per; if (hiB > n4) hiB = n4;
  uint2* myRegion = candBuf + (size_t)blockIdx.x * perBlockCap;
  for (long long i = lo + threadIdx.x; i < hiB; i += NT) {
    uint4 w = p4[i];
    uint32_t baseIdx = (uint32_t)(i << 2);
    uint32_t us[4] = { w.x & 0x7fffffffu, w.y & 0x7fffffffu,
                       w.z & 0x7fffffffu, w.w & 0x7fffffffu };
#pragma unroll
    for (int c = 0; c < 4; ++c) {
      uint32_t u = us[c];
      if ((u >> 20) == b1) {
        atomicAdd(&h[(u >> 8) & 0xFFFu], 1u);
        uint32_t p = atomicAdd(&lcount, 1u);
        if (p < perBlockCap) myRegion[p] = make_uint2(baseIdx + c, u);
      }
    }
  }
  __syncthreads();
  for (int i = threadIdx.x; i < 4096; i += NT)
    if (h[i]) atomicAdd(&hist2[i], h[i]);
  if (threadIdx.x == 0) {
    blockCounts[blockIdx.x] = lcount;
    if (lcount > perBlockCap) atomicOr(&meta[M_OVF], 1u);
  }
}

// ------- Pass 3: filter candidates to level-2 sub-bin, compact + hist3 -------
__global__ void k_pass3(const uint32_t* __restrict__ param, long long n,
                        uint32_t* __restrict__ meta,
                        const uint2* __restrict__ candBuf, uint32_t perBlockCap,
                        const uint32_t* __restrict__ blockCounts,
                        uint32_t* __restrict__ hist3,
                        uint2* __restrict__ cand2Buf, uint32_t cand2Cap) {
  __shared__ uint32_t h[256];
  __shared__ uint32_t sb1, sb2, sovf;
  if (threadIdx.x == 0) { sb1 = meta[M_B1]; sb2 = meta[M_B2]; sovf = meta[M_OVF]; }
  for (int i = threadIdx.x; i < 256; i += NT) h[i] = 0;
  __syncthreads();
  uint32_t b1 = sb1, b2 = sb2;
  if (!sovf) {
    uint32_t cnt = blockCounts[blockIdx.x];
    if (cnt > perBlockCap) cnt = perBlockCap;  // defensive
    const uint2* myRegion = candBuf + (size_t)blockIdx.x * perBlockCap;
    for (uint32_t i = threadIdx.x; i < cnt; i += NT) {
      uint2 e = myRegion[i];
      if (((e.y >> 8) & 0xFFFu) == b2) {
        atomicAdd(&h[e.y & 0xFFu], 1u);
        uint32_t pos = atomicAdd(&meta[M_CAND2], 1u);
        if (pos < cand2Cap) cand2Buf[pos] = e;
      }
    }
  } else {
    // fallback: candidate buffer overflowed -> re-scan full input
    long long stride = (long long)gridDim.x * NT;
    for (long long i = (long long)blockIdx.x * NT + threadIdx.x; i < n; i += stride) {
      uint32_t u = param[i] & 0x7fffffffu;
      if ((u >> 20) == b1 && ((u >> 8) & 0xFFFu) == b2) {
        atomicAdd(&h[u & 0xFFu], 1u);
        uint32_t pos = atomicAdd(&meta[M_CAND2], 1u);
        if (pos < cand2Cap) cand2Buf[pos] = make_uint2((uint32_t)i, u);
      }
    }
  }
  __syncthreads();
  for (int i = threadIdx.x; i < 256; i += NT)
    if (h[i]) atomicAdd(&hist3[i], h[i]);
}

// ------- Resolve: scan hist3 -> exact cutoff v, nLess, nTie; then compute
// tie index threshold I_thr (stable-sort semantics) -------
__global__ void k_resolve(const uint32_t* __restrict__ param, long long n,
                          uint32_t* __restrict__ meta,
                          const uint32_t* __restrict__ hist3,
                          const uint2* __restrict__ cand2Buf, uint32_t cand2Cap,
                          uint32_t jrank) {
  __shared__ uint32_t part[NT];
  __shared__ uint32_t sv, sntz;
  uint32_t c2 = meta[M_C2];
  uint32_t hv = (threadIdx.x < 256) ? hist3[threadIdx.x] : 0u;
  part[threadIdx.x] = hv;
  __syncthreads();
  for (int off = 1; off < NT; off <<= 1) {
    uint32_t y = (threadIdx.x >= (unsigned)off) ? part[threadIdx.x - off] : 0u;
    __syncthreads();
    part[threadIdx.x] += y;
    __syncthreads();
  }
  uint32_t cum = c2 + part[threadIdx.x] - hv;
  if (threadIdx.x < 256 && cum <= jrank && jrank < cum + hv) {
    uint32_t b3 = threadIdx.x;
    uint32_t v = (meta[M_B1] << 20) | (meta[M_B2] << 8) | b3;
    meta[M_B3] = b3; meta[M_V] = v;
    meta[M_NLESS] = cum; meta[M_NTIE] = hv; meta[M_NTZ] = jrank - cum;
    sv = v; sntz = jrank - cum;
  }
  __syncthreads();
  uint32_t v = sv, ntz = sntz;
  if (ntz == 0) {
    if (threadIdx.x == 0) meta[M_ITHR] = 0u;  // all ties get 1
    return;
  }
  uint32_t cand2Count = meta[M_CAND2];
  if (cand2Count <= cand2Cap) {
    uint32_t S = cand2Count;
    for (uint32_t e = threadIdx.x; e < S; e += NT) {
      uint2 ee = cand2Buf[e];
      if (ee.y != v) continue;
      uint32_t rank = 0;
      for (uint32_t s = 0; s < S; ++s) {
        uint2 o = cand2Buf[s];
        rank += (o.y == v && o.x < ee.x) ? 1u : 0u;
      }
      if (rank == ntz) meta[M_ITHR] = ee.x;
    }
  } else {
    // extreme fallback: scan entire input (correctness only; never expected)
    for (long long e = threadIdx.x; e < n; e += NT) {
      uint32_t u = param[e] & 0x7fffffffu;
      if (u != v) continue;
      uint32_t rank = 0;
      for (long long s = 0; s < n; ++s) {
        uint32_t u2 = param[s] & 0x7fffffffu;
        rank += (u2 == v && (uint32_t)s < (uint32_t)e) ? 1u : 0u;
      }
      if (rank == ntz) meta[M_ITHR] = (uint32_t)e;
    }
  }
}

// ------------- Pass 5: write mask -------------
__global__ void k_out(const uint32_t* __restrict__ param, long long n4,
                      const uint32_t* __restrict__ meta, float* __restrict__ out) {
  uint32_t v = meta[M_V];
  uint32_t ithr = meta[M_ITHR];
  const uint4* p4 = (const uint4*)param;
  float4* o4 = (float4*)out;
  long long stride = (long long)gridDim.x * NT;
  for (long long i = (long long)blockIdx.x * NT + threadIdx.x; i < n4; i += stride) {
    uint4 w = p4[i];
    uint32_t baseIdx = (uint32_t)(i << 2);
    float4 r;
    uint32_t ux = w.x & 0x7fffffffu, uy = w.y & 0x7fffffffu;
    uint32_t uz = w.z & 0x7fffffffu, uw = w.w & 0x7fffffffu;
    r.x = (ux > v || (ux == v && baseIdx + 0 >= ithr)) ? 1.0f : 0.0f;
    r.y = (uy > v || (uy == v && baseIdx + 1 >= ithr)) ? 1.0f : 0.0f;
    r.z = (uz > v || (uz == v && baseIdx + 2 >= ithr)) ? 1.0f : 0.0f;
    r.w = (uw > v || (uw == v && baseIdx + 3 >= ithr)) ? 1.0f : 0.0f;
    o4[i] = r;
  }
}

extern "C" void kernel_launch(void* const* d_in, const int* in_sizes, int n_in,
                              void* d_out, int out_size, void* d_ws, size_t ws_size,
                              hipStream_t stream) {
  const uint32_t* param = (const uint32_t*)d_in[0];
  float* out = (float*)d_out;
  long long n = (long long)in_sizes[0];        // 4096*16384 = 67108864, divisible by 4
  long long n4 = n >> 2;
  uint32_t jrank = (uint32_t)((1.0 - 0.5) * (double)n);  // int((1-k)*n) = 33554432

  // workspace layout
  uint8_t* ws = (uint8_t*)d_ws;
  uint32_t* meta  = (uint32_t*)ws;             // 32 u32
  uint32_t* hist1 = meta + 32;                 // 2048 u32
  uint32_t* hist2 = hist1 + 2048;              // 4096 u32
  uint32_t* hist3 = hist2 + 4096;              // 256 u32
  const int nzero = 32 + 2048 + 4096 + 256;    // 6432 u32
  uint32_t* blockCounts = hist3 + 256;         // BIG_BLOCKS u32
  size_t fixedBytes = (size_t)(nzero + BIG_BLOCKS) * 4;  // 33920 B (8-aligned)

  uint32_t cand2Cap = 0;
  if (ws_size > fixedBytes + 8) {
    size_t slots = (ws_size - fixedBytes) / 8;
    size_t c2 = slots / 8;                     // reserve ~1/8 for level-2 list
    if (c2 > 65536) c2 = 65536;
    cand2Cap = (uint32_t)c2;
  }
  uint2* cand2Buf = (uint2*)(ws + fixedBytes);
  uint2* candBuf = cand2Buf + cand2Cap;
  uint32_t perBlockCap = 0;
  {
    size_t candBytesOff = fixedBytes + (size_t)cand2Cap * 8;
    if (ws_size > candBytesOff + 8) {
      size_t slots = (ws_size - candBytesOff) / 8;
      size_t pbc = slots / BIG_BLOCKS;
      if (pbc > 65536) pbc = 65536;
      perBlockCap = (uint32_t)pbc;
    }
  }

  k_zero<<<(nzero + NT - 1) / NT, NT, 0, stream>>>(meta, nzero);
  k_hist1<<<BIG_BLOCKS, NT, 0, stream>>>(param, n4, hist1);
  k_select<<<1, NT, 0, stream>>>(hist1, 2048, nullptr, jrank, &meta[M_B1], &meta[M_C1]);
  k_pass2<<<BIG_BLOCKS, NT, 0, stream>>>(param, n, meta, hist2, candBuf, perBlockCap, blockCounts);
  k_select<<<1, NT, 0, stream>>>(hist2, 4096, &meta[M_C1], jrank, &meta[M_B2], &meta[M_C2]);
  k_pass3<<<BIG_BLOCKS, NT, 0, stream>>>(param, n, meta, candBuf, perBlockCap, blockCounts,
                                         hist3, cand2Buf, cand2Cap);
  k_resolve<<<1, NT, 0, stream>>>(param, n, meta, hist3, cand2Buf, cand2Cap, jrank);
  k_out<<<BIG_BLOCKS, NT, 0, stream>>>(param, n4, meta, out);
}